// Round 7
// baseline (862.620 us; speedup 1.0000x reference)
//
#include <hip/hip_runtime.h>
#include <math.h>

#define N_NODES 16000
#define NGRAPH  16
#define NPG     1000      // nodes per graph
#define H       64
#define KNN     20
#define DIN     8
#define HID     32
#define NLAYERS 4
#define CD      8
#define EPS_BN  1e-5f
#define TI      16        // i-nodes per kNN block
#define IBLK    63        // ceil(1000/16)
#define INFF    __builtin_inff()
#define PADF    1.0e30f   // finite pad value

// ---------------------------------------------------------------------------
// lc_encode: x[16000,8] -> Linear(8,32)+ELU -> Linear(32,64)+ELU -> h ; also sq
// wave per node, 4 nodes/block
__global__ __launch_bounds__(256) void k_lc_encode(
    const float* __restrict__ x, const float* __restrict__ W1, const float* __restrict__ b1,
    const float* __restrict__ W2, const float* __restrict__ b2,
    float* __restrict__ h, float* __restrict__ sq)
{
    __shared__ float sW1[DIN * HID];
    __shared__ float sb1[HID];
    __shared__ float sW2[HID * H];
    __shared__ float sb2[H];
    __shared__ float sx[4][DIN];
    __shared__ float sa1[4][HID];

    int t = threadIdx.x;
    for (int ix = t; ix < DIN * HID; ix += 256) sW1[ix] = W1[ix];
    for (int ix = t; ix < HID * H;  ix += 256) sW2[ix] = W2[ix];
    if (t < HID) sb1[t] = b1[t];
    if (t < H)   sb2[t] = b2[t];

    int w = t >> 6, lane = t & 63;
    int i = blockIdx.x * 4 + w;
    if (lane < DIN) sx[w][lane] = x[i * DIN + lane];
    __syncthreads();

    // stage 1 (32 outputs; lanes 32..63 duplicate to keep flow uniform)
    int c = lane & 31;
    float a1 = sb1[c];
#pragma unroll
    for (int k = 0; k < DIN; k++) a1 += sx[w][k] * sW1[k * HID + c];
    a1 = a1 > 0.f ? a1 : expm1f(a1);
    if (lane < HID) sa1[w][lane] = a1;
    __syncthreads();

    // stage 2 (64 outputs)
    float acc = sb2[lane];
#pragma unroll
    for (int k = 0; k < HID; k++) acc += sa1[w][k] * sW2[k * H + lane];
    acc = acc > 0.f ? acc : expm1f(acc);
    h[i * H + lane] = acc;

    float s = acc * acc;
#pragma unroll
    for (int off = 32; off > 0; off >>= 1) s += __shfl_xor(s, off);
    if (lane == 0) sq[i] = s;
}

// ---------------------------------------------------------------------------
// Fused kNN: per block 16 i-nodes of one graph. d2(i,j) = sq_i + sq_j - 2*dot.
// Each wave owns 4 i's; lane covers j; EXACT f32 d2 in VGPRs.
//
// SPILL LEDGER (hard-won): allocator refuses to cross the 128-VGPR step here;
// overflows spill with VGPR pinned at 128 and GB-scale scratch:
//   r0: runtime-indexed d2 array                    -> spill (78 MB)
//   r1/r6: kc UNROLL 2 + static 32-bit selection    -> NO SPILL (80-88 VGPR)
//   r3/r4/r5: kc FULL unroll (any selection)        -> spill (2.6-3.3 GB)
// => kc stays UNROLL 2; all d2k indices static; selection state 32-bit.
//
// r7 change: dist phase was LDS-READ-ISSUE-bound (768 ds_read_b128/wave,
// VALUBusy 48%, 0 bank conflicts). Widen rounds: 4 j-tiles (256 j) per
// barrier, 4 rounds -> per kc: 4 shj + 4 shi reads feed 16 fma4 (vs 6 reads
// for 8). 768 -> 512 reads/wave (-33%); shi re-reads halve. The round's 16
// d2k slots ARE the accumulators (init 0, accumulate, finalize in place) so
// register count stays ~r6. LDS 37.9 -> ~69 KB (2 blocks/CU).
//
// Selection: per-lane top-2 cache (r6, proven): build branchless top-2 scan;
// per round 4 interleaved (v,j) lex butterflies (jax tie order); owner pops
// head<-second; rare exact refill from d2k. e->j: j=(e>>2)*256+(e&3)*64+lane
// (strictly increasing in e, so smaller-e tie preference == smaller-j).
__global__ __launch_bounds__(256, 2) void k_knn(
    const float* __restrict__ h, const float* __restrict__ sq, int* __restrict__ knn)
{
    __shared__ float shi[TI * H];        // 16 rows x 64 (broadcast reads -> no pad)
    __shared__ float ssqi[TI];
    __shared__ float shj[4][64 * 64];    // 4 tiles x 64 rows x 16 float4, xor-swizzled
    __shared__ float ssqj[4][64];

    int g  = blockIdx.x / IBLK;
    int ib = blockIdx.x % IBLK;
    int i0 = ib * TI;                    // graph-local
    int tid = threadIdx.x, w = tid >> 6, lane = tid & 63;
    const float* hg  = h  + (size_t)g * NPG * H;
    const float* sqg = sq + (size_t)g * NPG;

    // stage hi tile: 16x64 floats = 256 float4, one per thread
    {
        int row = tid >> 4, c4 = tid & 15;
        int i = i0 + row;
        float4 v = make_float4(0.f, 0.f, 0.f, 0.f);
        if (i < NPG) v = *(const float4*)(hg + i * H + c4 * 4);
        *(float4*)(shi + row * H + c4 * 4) = v;
        if (tid < TI) ssqi[tid] = (i0 + tid < NPG) ? sqg[i0 + tid] : 0.f;
    }
    __syncthreads();

    float sqi[4];
#pragma unroll
    for (int ii = 0; ii < 4; ii++) sqi[ii] = ssqi[w * 4 + ii];

    float d2k[4][16];                    // EXACT d2; e <-> j = (e>>2)*256+(e&3)*64+lane

#pragma unroll
    for (int p = 0; p < 4; p++) {
        if (p) __syncthreads();          // previous round's compute done
        // stage 4 j-tiles (256 nodes x 64 floats), xor-swizzled at float4 level
#pragma unroll
        for (int s = 0; s < 16; s++) {
            int f = tid + 256 * s;       // 0..4095
            int q  = f >> 10;            // tile 0..3
            int fi = f & 1023;
            int row = fi >> 4, c4 = fi & 15;
            int jl = p * 256 + q * 64 + row;
            float4 v = make_float4(0.f, 0.f, 0.f, 0.f);
            if (jl < NPG) v = *(const float4*)(hg + jl * H + c4 * 4);
            *(float4*)(&shj[q][(row * 16 + (c4 ^ (row & 15))) * 4]) = v;
        }
        {
            int jl = p * 256 + tid;
            ssqj[tid >> 6][tid & 63] = (jl < NPG) ? sqg[jl] : 0.f;
        }
        // this round's 16 d2k slots double as accumulators
#pragma unroll
        for (int ii = 0; ii < 4; ii++) {
            d2k[ii][p * 4 + 0] = 0.f; d2k[ii][p * 4 + 1] = 0.f;
            d2k[ii][p * 4 + 2] = 0.f; d2k[ii][p * 4 + 3] = 0.f;
        }
        __syncthreads();

#pragma unroll 2
        for (int kc = 0; kc < 16; kc++) {
            int bo = (lane * 16 + (kc ^ (lane & 15))) * 4;
            float4 b0 = *(const float4*)(&shj[0][bo]);
            float4 b1 = *(const float4*)(&shj[1][bo]);
            float4 b2 = *(const float4*)(&shj[2][bo]);
            float4 b3 = *(const float4*)(&shj[3][bo]);
            float4 r0 = *(const float4*)(shi + (w * 4 + 0) * H + kc * 4);
            float4 r1 = *(const float4*)(shi + (w * 4 + 1) * H + kc * 4);
            float4 r2 = *(const float4*)(shi + (w * 4 + 2) * H + kc * 4);
            float4 r3 = *(const float4*)(shi + (w * 4 + 3) * H + kc * 4);
            d2k[0][p*4+0] += r0.x*b0.x + r0.y*b0.y + r0.z*b0.z + r0.w*b0.w;
            d2k[1][p*4+0] += r1.x*b0.x + r1.y*b0.y + r1.z*b0.z + r1.w*b0.w;
            d2k[2][p*4+0] += r2.x*b0.x + r2.y*b0.y + r2.z*b0.z + r2.w*b0.w;
            d2k[3][p*4+0] += r3.x*b0.x + r3.y*b0.y + r3.z*b0.z + r3.w*b0.w;
            d2k[0][p*4+1] += r0.x*b1.x + r0.y*b1.y + r0.z*b1.z + r0.w*b1.w;
            d2k[1][p*4+1] += r1.x*b1.x + r1.y*b1.y + r1.z*b1.z + r1.w*b1.w;
            d2k[2][p*4+1] += r2.x*b1.x + r2.y*b1.y + r2.z*b1.z + r2.w*b1.w;
            d2k[3][p*4+1] += r3.x*b1.x + r3.y*b1.y + r3.z*b1.z + r3.w*b1.w;
            d2k[0][p*4+2] += r0.x*b2.x + r0.y*b2.y + r0.z*b2.z + r0.w*b2.w;
            d2k[1][p*4+2] += r1.x*b2.x + r1.y*b2.y + r1.z*b2.z + r1.w*b2.w;
            d2k[2][p*4+2] += r2.x*b2.x + r2.y*b2.y + r2.z*b2.z + r2.w*b2.w;
            d2k[3][p*4+2] += r3.x*b2.x + r3.y*b2.y + r3.z*b2.z + r3.w*b2.w;
            d2k[0][p*4+3] += r0.x*b3.x + r0.y*b3.y + r0.z*b3.z + r0.w*b3.w;
            d2k[1][p*4+3] += r1.x*b3.x + r1.y*b3.y + r1.z*b3.z + r1.w*b3.w;
            d2k[2][p*4+3] += r2.x*b3.x + r2.y*b3.y + r2.z*b3.z + r2.w*b3.w;
            d2k[3][p*4+3] += r3.x*b3.x + r3.y*b3.y + r3.z*b3.z + r3.w*b3.w;
        }

        // finalize this round's 16 slots in place
#pragma unroll
        for (int q = 0; q < 4; q++) {
            float sqjv = ssqj[q][lane];
            int jt = p * 256 + q * 64 + lane;
            bool ok = jt < NPG;
#pragma unroll
            for (int ii = 0; ii < 4; ii++) {
                float acc = d2k[ii][p * 4 + q];
                d2k[ii][p * 4 + q] = ok ? (sqi[ii] + sqjv - 2.f * acc) : PADF;
            }
        }
    }

    // ---- build per-lane top-2 cache + used mask (branchless, static) ------
    float qv0[4], qv1[4];
    int   qe0[4], qe1[4];
    unsigned used[4];
    int   myj[4];
#pragma unroll
    for (int ii = 0; ii < 4; ii++) {
        float v0 = PADF, v1 = PADF;
        int e0 = 0, e1 = 0;
#pragma unroll
        for (int e = 0; e < 16; e++) {
            float s = d2k[ii][e];
            bool b0 = (s < v0);
            bool b1 = (s < v1) && !b0;
            v1 = b0 ? v0 : (b1 ? s : v1);
            e1 = b0 ? e0 : (b1 ? e : e1);
            v0 = b0 ? s : v0;
            e0 = b0 ? e : e0;
        }
        qv0[ii] = v0; qe0[ii] = e0;
        qv1[ii] = v1; qe1[ii] = e1;
        used[ii] = ((v0 < PADF) ? (1u << e0) : 0u) | ((v1 < PADF) ? (1u << e1) : 0u);
        myj[ii] = 0;
    }

    // ---- 20 extraction rounds: interleaved (v,j) lex butterflies ----------
#pragma unroll 1
    for (int round = 0; round < KNN; round++) {
        float mv[4]; int mj[4];
#pragma unroll
        for (int ii = 0; ii < 4; ii++) {
            mv[ii] = qv0[ii];
            mj[ii] = ((qe0[ii] >> 2) << 8) + ((qe0[ii] & 3) << 6) + lane;
        }
#pragma unroll
        for (int off = 1; off < 64; off <<= 1)
#pragma unroll
            for (int ii = 0; ii < 4; ii++) {
                float ov = __shfl_xor(mv[ii], off);
                int   oj = __shfl_xor(mj[ii], off);
                bool less = (ov < mv[ii]) || (ov == mv[ii] && oj < mj[ii]);
                if (less) { mv[ii] = ov; mj[ii] = oj; }
            }
#pragma unroll
        for (int ii = 0; ii < 4; ii++) {
            if (lane == round) myj[ii] = mj[ii];
            if ((mj[ii] & 63) == lane) {         // unique owner (j mod 64 == lane)
                qv0[ii] = qv1[ii]; qe0[ii] = qe1[ii];
                qv1[ii] = PADF;    qe1[ii] = 0;
                if (qv0[ii] >= PADF) {           // placeholder at head: refill
                    float v0 = PADF, v1 = PADF;
                    int e0 = 0, e1 = 0;
#pragma unroll
                    for (int e = 0; e < 16; e++) {
                        float s = (((used[ii] >> e) & 1u) == 0u) ? d2k[ii][e] : PADF;
                        bool b0 = (s < v0);
                        bool b1 = (s < v1) && !b0;
                        v1 = b0 ? v0 : (b1 ? s : v1);
                        e1 = b0 ? e0 : (b1 ? e : e1);
                        v0 = b0 ? s : v0;
                        e0 = b0 ? e : e0;
                    }
                    qv0[ii] = v0; qe0[ii] = e0;
                    qv1[ii] = v1; qe1[ii] = e1;
                    used[ii] |= ((v0 < PADF) ? (1u << e0) : 0u)
                              | ((v1 < PADF) ? (1u << e1) : 0u);
                }
            }
        }
    }

    // ---- write: lane r holds winner of round r ----------------------------
#pragma unroll
    for (int ii = 0; ii < 4; ii++) {
        int i_loc = i0 + w * 4 + ii;
        if (lane < KNN && i_loc < NPG)
            knn[(size_t)(g * NPG + i_loc) * KNN + lane] = g * NPG + myj[ii];
    }
}

// ---------------------------------------------------------------------------
// T = h @ (W1 - W2) + b ; U = h @ W2.   W: [128][64] (rows 0..63 = x_i part).
__global__ __launch_bounds__(256) void k_tu(
    const float* __restrict__ h, const float* __restrict__ W, const float* __restrict__ b,
    float* __restrict__ T, float* __restrict__ U)
{
    __shared__ float sWd[H * H];
    __shared__ float sW2[H * H];
    __shared__ float sh[16 * H];
    __shared__ float sb[H];
    int t = threadIdx.x;
    for (int ix = t; ix < H * H; ix += 256) {
        float w1 = W[ix], w2 = W[H * H + ix];
        sWd[ix] = w1 - w2; sW2[ix] = w2;
    }
    if (t < H) sb[t] = b[t];
    int i0 = blockIdx.x * 16;
    {
        int row = t >> 4, c4 = t & 15;
        *(float4*)(sh + row * H + c4 * 4) = *(const float4*)(h + (size_t)(i0 + row) * H + c4 * 4);
    }
    __syncthreads();

    int lane = t & 63, w = t >> 6;
    int nl = lane >> 4, cg = lane & 15;
    int node = w * 4 + nl;
    float4 tT = make_float4(0.f, 0.f, 0.f, 0.f);
    float4 tU = make_float4(0.f, 0.f, 0.f, 0.f);
#pragma unroll
    for (int e = 0; e < H; e++) {
        float hv = sh[node * H + e];
        float4 wd = *(const float4*)(sWd + e * H + cg * 4);
        float4 w2 = *(const float4*)(sW2 + e * H + cg * 4);
        tT.x += hv * wd.x; tT.y += hv * wd.y; tT.z += hv * wd.z; tT.w += hv * wd.w;
        tU.x += hv * w2.x; tU.y += hv * w2.y; tU.z += hv * w2.z; tU.w += hv * w2.w;
    }
    float4 bb = *(const float4*)(sb + cg * 4);
    tT.x += bb.x; tT.y += bb.y; tT.z += bb.z; tT.w += bb.w;
    int i = i0 + node;
    *(float4*)(T + (size_t)i * H + cg * 4) = tT;
    *(float4*)(U + (size_t)i * H + cg * 4) = tU;
}

// ---------------------------------------------------------------------------
// Aggregate: h_new[i][c] = h[i][c] + a*ELU(sel_k (T[i][c]+U[j_k][c])) + (be - a*m)
// sel = max if a>=0 else min (ELU monotone). Also writes sq(h_new).
__global__ __launch_bounds__(256) void k_aggr(
    const float* __restrict__ hsrc, const float* __restrict__ T, const float* __restrict__ U,
    const int* __restrict__ knn,
    const float* __restrict__ bn_g, const float* __restrict__ bn_b,
    const float* __restrict__ bn_m, const float* __restrict__ bn_v,
    float* __restrict__ hdst, float* __restrict__ sqdst)
{
    int t = threadIdx.x, w = t >> 6, lane = t & 63;
    int i = blockIdx.x * 4 + w;
    float a = bn_g[lane] * rsqrtf(bn_v[lane] + EPS_BN);
    float cshift = bn_b[lane] - a * bn_m[lane];
    float tv = T[(size_t)i * H + lane];
    int idx[KNN];
#pragma unroll
    for (int k = 0; k < KNN; k++) idx[k] = knn[(size_t)i * KNN + k];
    float mx = -INFF, mn = INFF;
#pragma unroll
    for (int k = 0; k < KNN; k++) {
        float z = tv + U[(size_t)idx[k] * H + lane];
        mx = fmaxf(mx, z); mn = fminf(mn, z);
    }
    float zsel = (a >= 0.f) ? mx : mn;
    float e = zsel > 0.f ? zsel : expm1f(zsel);
    float val = hsrc[(size_t)i * H + lane] + a * e + cshift;
    hdst[(size_t)i * H + lane] = val;
    float s = val * val;
#pragma unroll
    for (int off = 32; off > 0; off >>= 1) s += __shfl_xor(s, off);
    if (lane == 0) sqdst[i] = s;
}

// ---------------------------------------------------------------------------
// Output heads. 16 nodes/block (wave per node, 4 reps). out layout:
// [0,128000): out [16000,8] | [128000,144000): sp | [144000,160000): batch (f32)
__global__ __launch_bounds__(256) void k_heads(
    const float* __restrict__ h,
    const float* __restrict__ oW1, const float* __restrict__ ob1,
    const float* __restrict__ oW2, const float* __restrict__ ob2,
    const float* __restrict__ oW3, const float* __restrict__ ob3,
    const float* __restrict__ pW1, const float* __restrict__ pb1,
    const float* __restrict__ pW2, const float* __restrict__ pb2,
    const float* __restrict__ pW3, const float* __restrict__ pb3,
    float* __restrict__ out)
{
    __shared__ float soW1[H * 64], soW2[64 * 32], soW3[32 * CD];
    __shared__ float spW1s[H * 64], spW2s[64 * 32], spW3s[32];
    __shared__ float sob1[64], sob2[32], sob3[CD], spb1s[64], spb2s[32], spb3s[1];
    __shared__ float sh[4][H];
    __shared__ float sa[4][64], ssp[4][64];
    __shared__ float so2[4][32], ssp2[4][32];

    int t = threadIdx.x, w = t >> 6, lane = t & 63;
    for (int ix = t; ix < H * 64; ix += 256) { soW1[ix] = oW1[ix]; spW1s[ix] = pW1[ix]; }
    for (int ix = t; ix < 64 * 32; ix += 256) { soW2[ix] = oW2[ix]; spW2s[ix] = pW2[ix]; }
    for (int ix = t; ix < 32 * CD; ix += 256) soW3[ix] = oW3[ix];
    if (t < 32) spW3s[t] = pW3[t];
    if (t < 64) { sob1[t] = ob1[t]; spb1s[t] = pb1[t]; }
    if (t < 32) { sob2[t] = ob2[t]; spb2s[t] = pb2[t]; }
    if (t < CD) sob3[t] = ob3[t];
    if (t == 0) spb3s[0] = pb3[0];
    __syncthreads();

    for (int rep = 0; rep < 4; rep++) {
        int i = blockIdx.x * 16 + rep * 4 + w;
        sh[w][lane] = h[(size_t)i * H + lane];
        __syncthreads();
        float a1 = sob1[lane], p1 = spb1s[lane];
#pragma unroll
        for (int k = 0; k < H; k++) {
            float hv = sh[w][k];
            a1 += hv * soW1[k * 64 + lane];
            p1 += hv * spW1s[k * 64 + lane];
        }
        a1 = a1 > 0.f ? a1 : expm1f(a1);
        p1 = p1 > 0.f ? p1 : expm1f(p1);
        sa[w][lane] = a1; ssp[w][lane] = p1;
        __syncthreads();
        if (lane < 32) {
            float o2 = sob2[lane], q2 = spb2s[lane];
#pragma unroll
            for (int k = 0; k < 64; k++) {
                o2 += sa[w][k] * soW2[k * 32 + lane];
                q2 += ssp[w][k] * spW2s[k * 32 + lane];
            }
            o2 = o2 > 0.f ? o2 : expm1f(o2);
            q2 = q2 > 0.f ? q2 : expm1f(q2);
            so2[w][lane] = o2; ssp2[w][lane] = q2;
        }
        __syncthreads();
        if (lane < CD) {
            float o3 = sob3[lane];
#pragma unroll
            for (int k = 0; k < 32; k++) o3 += so2[w][k] * soW3[k * CD + lane];
            out[(size_t)i * CD + lane] = o3;
        }
        if (lane == 32) {
            float s3 = spb3s[0];
#pragma unroll
            for (int k = 0; k < 32; k++) s3 += ssp2[w][k] * spW3s[k];
            out[(size_t)N_NODES * CD + i] = s3;
        }
        if (lane == 33) out[(size_t)N_NODES * CD + N_NODES + i] = (float)(i / NPG);
        __syncthreads();
    }
}

// ---------------------------------------------------------------------------
extern "C" void kernel_launch(void* const* d_in, const int* in_sizes, int n_in,
                              void* d_out, int out_size, void* d_ws, size_t ws_size,
                              hipStream_t stream)
{
    const float* x     = (const float*)d_in[0];
    // d_in[1] = batch (values reproduced analytically)
    const float* lcW1  = (const float*)d_in[2];  const float* lcb1 = (const float*)d_in[3];
    const float* lcW2  = (const float*)d_in[4];  const float* lcb2 = (const float*)d_in[5];
    const float* convW = (const float*)d_in[6];  const float* convb = (const float*)d_in[7];
    const float* bn_g  = (const float*)d_in[8];  const float* bn_b = (const float*)d_in[9];
    const float* bn_m  = (const float*)d_in[10]; const float* bn_v = (const float*)d_in[11];
    const float* outW1 = (const float*)d_in[12]; const float* outb1 = (const float*)d_in[13];
    const float* outW2 = (const float*)d_in[14]; const float* outb2 = (const float*)d_in[15];
    const float* outW3 = (const float*)d_in[16]; const float* outb3 = (const float*)d_in[17];
    const float* spW1  = (const float*)d_in[18]; const float* spb1 = (const float*)d_in[19];
    const float* spW2  = (const float*)d_in[20]; const float* spb2 = (const float*)d_in[21];
    const float* spW3  = (const float*)d_in[22]; const float* spb3 = (const float*)d_in[23];

    float* ws  = (float*)d_ws;
    float* hA  = ws;                       // 1,024,000 floats
    float* hB  = hA + (size_t)N_NODES * H;
    float* sqA = hB + (size_t)N_NODES * H;
    float* sqB = sqA + N_NODES;
    float* T   = sqB + N_NODES;
    float* U   = T + (size_t)N_NODES * H;
    int*   knn = (int*)(U + (size_t)N_NODES * H);

    k_lc_encode<<<N_NODES / 4, 256, 0, stream>>>(x, lcW1, lcb1, lcW2, lcb2, hA, sqA);

    float* src = hA; float* ssq = sqA; float* dst = hB; float* dsq = sqB;
    for (int l = 0; l < NLAYERS; l++) {
        k_knn<<<NGRAPH * IBLK, 256, 0, stream>>>(src, ssq, knn);
        k_tu<<<N_NODES / 16, 256, 0, stream>>>(src, convW + (size_t)l * 2 * H * H,
                                               convb + (size_t)l * H, T, U);
        k_aggr<<<N_NODES / 4, 256, 0, stream>>>(src, T, U, knn,
                                                bn_g + (size_t)l * H, bn_b + (size_t)l * H,
                                                bn_m + (size_t)l * H, bn_v + (size_t)l * H,
                                                dst, dsq);
        float* tmp = src; src = dst; dst = tmp;
        tmp = ssq; ssq = dsq; dsq = tmp;
    }

    k_heads<<<N_NODES / 16, 256, 0, stream>>>(src,
        outW1, outb1, outW2, outb2, outW3, outb3,
        spW1, spb1, spW2, spb2, spW3, spb3, (float*)d_out);
}

// Round 8
// 826.128 us; speedup vs baseline: 1.0442x; 1.0442x over previous
//
#include <hip/hip_runtime.h>
#include <math.h>

#define N_NODES 16000
#define NGRAPH  16
#define NPG     1000      // nodes per graph
#define H       64
#define KNN     20
#define DIN     8
#define HID     32
#define NLAYERS 4
#define CD      8
#define EPS_BN  1e-5f
#define TI      16        // i-nodes per kNN block
#define IBLK    63        // ceil(1000/16)
#define INFF    __builtin_inff()
#define PADF    1.0e30f   // finite pad value

// ---------------------------------------------------------------------------
// lc_encode: x[16000,8] -> Linear(8,32)+ELU -> Linear(32,64)+ELU -> h ; also sq
// wave per node, 4 nodes/block
__global__ __launch_bounds__(256) void k_lc_encode(
    const float* __restrict__ x, const float* __restrict__ W1, const float* __restrict__ b1,
    const float* __restrict__ W2, const float* __restrict__ b2,
    float* __restrict__ h, float* __restrict__ sq)
{
    __shared__ float sW1[DIN * HID];
    __shared__ float sb1[HID];
    __shared__ float sW2[HID * H];
    __shared__ float sb2[H];
    __shared__ float sx[4][DIN];
    __shared__ float sa1[4][HID];

    int t = threadIdx.x;
    for (int ix = t; ix < DIN * HID; ix += 256) sW1[ix] = W1[ix];
    for (int ix = t; ix < HID * H;  ix += 256) sW2[ix] = W2[ix];
    if (t < HID) sb1[t] = b1[t];
    if (t < H)   sb2[t] = b2[t];

    int w = t >> 6, lane = t & 63;
    int i = blockIdx.x * 4 + w;
    if (lane < DIN) sx[w][lane] = x[i * DIN + lane];
    __syncthreads();

    // stage 1 (32 outputs; lanes 32..63 duplicate to keep flow uniform)
    int c = lane & 31;
    float a1 = sb1[c];
#pragma unroll
    for (int k = 0; k < DIN; k++) a1 += sx[w][k] * sW1[k * HID + c];
    a1 = a1 > 0.f ? a1 : expm1f(a1);
    if (lane < HID) sa1[w][lane] = a1;
    __syncthreads();

    // stage 2 (64 outputs)
    float acc = sb2[lane];
#pragma unroll
    for (int k = 0; k < HID; k++) acc += sa1[w][k] * sW2[k * H + lane];
    acc = acc > 0.f ? acc : expm1f(acc);
    h[i * H + lane] = acc;

    float s = acc * acc;
#pragma unroll
    for (int off = 32; off > 0; off >>= 1) s += __shfl_xor(s, off);
    if (lane == 0) sq[i] = s;
}

// ---------------------------------------------------------------------------
// Fused kNN + TU: per block 16 i-nodes of one graph.
// d2(i,j) = sq_i + sq_j - 2*dot; exact f32 d2 in VGPRs; then selection; then
// T = h@(W1-W2)+b, U = h@W2 for the same 16 rows (shi already staged, shj
// dead after dist -> reused as the 2x(64x64) weight store).
//
// SPILL LEDGER (hard-won): allocator refuses to cross the 128-VGPR step here;
// overflows spill with VGPR pinned at 128 and GB-scale scratch:
//   r0: runtime-indexed d2 array                    -> spill (78 MB)
//   r1/r6: kc UNROLL 2 + static 32-bit selection    -> NO SPILL (80-88 VGPR)
//   r3/r4/r5: kc FULL unroll (any selection)        -> spill (2.6-3.3 GB)
//   r7: 4-tile rounds (69KB LDS, 2 blk/CU)          -> no spill but SLOWER
// => kc stays UNROLL 2; 2-tile rounds; all d2k indices static; 32-bit sel.
//
// Phase order: dist(8 rounds) -> barrier -> stage weights into shj (ds_writes
// retire under selection) -> selection (no shj storage access; bpermute is
// crossbar-only) -> knn write -> barrier (weights visible) -> TU -> store.
__global__ __launch_bounds__(256, 2) void k_knn(
    const float* __restrict__ h, const float* __restrict__ sq, int* __restrict__ knn,
    const float* __restrict__ Wl, const float* __restrict__ bl,
    float* __restrict__ T, float* __restrict__ U)
{
    __shared__ float shi[TI * H];        // 16 rows x 64 (broadcast reads -> no pad)
    __shared__ float ssqi[TI];
    __shared__ float shj[2][64 * 64];    // dist: 2 j-tiles (xor-swizzled) | TU: Wd, W2
    __shared__ float ssqj[2][64];

    int g  = blockIdx.x / IBLK;
    int ib = blockIdx.x % IBLK;
    int i0 = ib * TI;                    // graph-local
    int t = threadIdx.x, w = t >> 6, lane = t & 63;
    const float* hg  = h  + (size_t)g * NPG * H;
    const float* sqg = sq + (size_t)g * NPG;

    // stage hi tile: 16x64 floats = 256 float4, one per thread
    {
        int row = t >> 4, c4 = t & 15;
        int i = i0 + row;
        float4 v = make_float4(0.f, 0.f, 0.f, 0.f);
        if (i < NPG) v = *(const float4*)(hg + i * H + c4 * 4);
        *(float4*)(shi + row * H + c4 * 4) = v;
        if (t < TI) ssqi[t] = (i0 + t < NPG) ? sqg[i0 + t] : 0.f;
    }
    __syncthreads();

    float sqi[4];
#pragma unroll
    for (int ii = 0; ii < 4; ii++) sqi[ii] = ssqi[w * 4 + ii];

    float d2k[4][16];                    // EXACT d2, element e <-> j = e*64+lane

#pragma unroll
    for (int rg = 0; rg < 8; rg++) {
        if (rg) __syncthreads();         // previous tile-pair's compute done
        // stage 2 j-tiles (128 nodes x 64 floats), xor-swizzled at float4 level
#pragma unroll
        for (int p = 0; p < 8; p++) {
            int f = t + 256 * p;         // 0..2047
            int tile = f >> 10;
            int fi = f & 1023;
            int row = fi >> 4, c4 = fi & 15;
            int jl = rg * 128 + tile * 64 + row;
            float4 v = make_float4(0.f, 0.f, 0.f, 0.f);
            if (jl < NPG) v = *(const float4*)(hg + jl * H + c4 * 4);
            *(float4*)(&shj[tile][(row * 16 + (c4 ^ (row & 15))) * 4]) = v;
        }
        if (t < 128) {
            int jl = rg * 128 + t;
            ssqj[t >> 6][t & 63] = (jl < NPG) ? sqg[jl] : 0.f;
        }
        __syncthreads();

        float sqj0 = ssqj[0][lane];
        float sqj1 = ssqj[1][lane];
        float a00 = 0.f, a10 = 0.f, a20 = 0.f, a30 = 0.f;   // tile 0
        float a01 = 0.f, a11 = 0.f, a21 = 0.f, a31 = 0.f;   // tile 1
#pragma unroll 2
        for (int kc = 0; kc < 16; kc++) {
            int bo = (lane * 16 + (kc ^ (lane & 15))) * 4;
            float4 b0 = *(const float4*)(&shj[0][bo]);
            float4 b1 = *(const float4*)(&shj[1][bo]);
            float4 r0 = *(const float4*)(shi + (w * 4 + 0) * H + kc * 4);
            float4 r1 = *(const float4*)(shi + (w * 4 + 1) * H + kc * 4);
            float4 r2 = *(const float4*)(shi + (w * 4 + 2) * H + kc * 4);
            float4 r3 = *(const float4*)(shi + (w * 4 + 3) * H + kc * 4);
            a00 += r0.x * b0.x + r0.y * b0.y + r0.z * b0.z + r0.w * b0.w;
            a10 += r1.x * b0.x + r1.y * b0.y + r1.z * b0.z + r1.w * b0.w;
            a20 += r2.x * b0.x + r2.y * b0.y + r2.z * b0.z + r2.w * b0.w;
            a30 += r3.x * b0.x + r3.y * b0.y + r3.z * b0.z + r3.w * b0.w;
            a01 += r0.x * b1.x + r0.y * b1.y + r0.z * b1.z + r0.w * b1.w;
            a11 += r1.x * b1.x + r1.y * b1.y + r1.z * b1.z + r1.w * b1.w;
            a21 += r2.x * b1.x + r2.y * b1.y + r2.z * b1.z + r2.w * b1.w;
            a31 += r3.x * b1.x + r3.y * b1.y + r3.z * b1.z + r3.w * b1.w;
        }
        int j0 = rg * 128 + lane;
        int j1 = j0 + 64;
        bool ok0 = (j0 < NPG), ok1 = (j1 < NPG);
        d2k[0][rg * 2 + 0] = ok0 ? (sqi[0] + sqj0 - 2.f * a00) : PADF;
        d2k[1][rg * 2 + 0] = ok0 ? (sqi[1] + sqj0 - 2.f * a10) : PADF;
        d2k[2][rg * 2 + 0] = ok0 ? (sqi[2] + sqj0 - 2.f * a20) : PADF;
        d2k[3][rg * 2 + 0] = ok0 ? (sqi[3] + sqj0 - 2.f * a30) : PADF;
        d2k[0][rg * 2 + 1] = ok1 ? (sqi[0] + sqj1 - 2.f * a01) : PADF;
        d2k[1][rg * 2 + 1] = ok1 ? (sqi[1] + sqj1 - 2.f * a11) : PADF;
        d2k[2][rg * 2 + 1] = ok1 ? (sqi[2] + sqj1 - 2.f * a21) : PADF;
        d2k[3][rg * 2 + 1] = ok1 ? (sqi[3] + sqj1 - 2.f * a31) : PADF;
    }

    // ---- dist done: stage TU weights into shj (writes retire under sel) ---
    __syncthreads();                     // all waves done reading shj
#pragma unroll
    for (int s = 0; s < 4; s++) {
        int ix4 = t + 256 * s;           // float4 index 0..1023
        float4 w1 = *(const float4*)(Wl + ix4 * 4);
        float4 w2 = *(const float4*)(Wl + 4096 + ix4 * 4);
        *(float4*)(&shj[0][ix4 * 4]) =
            make_float4(w1.x - w2.x, w1.y - w2.y, w1.z - w2.z, w1.w - w2.w);
        *(float4*)(&shj[1][ix4 * 4]) = w2;
    }

    // ---- build per-lane top-2 cache + used mask (branchless, static) ------
    float qv0[4], qv1[4];
    int   qe0[4], qe1[4];
    unsigned used[4];
    int   myj[4];
#pragma unroll
    for (int ii = 0; ii < 4; ii++) {
        float v0 = PADF, v1 = PADF;
        int e0 = 0, e1 = 0;
#pragma unroll
        for (int e = 0; e < 16; e++) {
            float s = d2k[ii][e];
            bool b0 = (s < v0);
            bool b1 = (s < v1) && !b0;
            v1 = b0 ? v0 : (b1 ? s : v1);
            e1 = b0 ? e0 : (b1 ? e : e1);
            v0 = b0 ? s : v0;
            e0 = b0 ? e : e0;
        }
        qv0[ii] = v0; qe0[ii] = e0;
        qv1[ii] = v1; qe1[ii] = e1;
        used[ii] = ((v0 < PADF) ? (1u << e0) : 0u) | ((v1 < PADF) ? (1u << e1) : 0u);
        myj[ii] = 0;
    }

    // ---- 20 extraction rounds: interleaved (v,j) lex butterflies ----------
#pragma unroll 1
    for (int round = 0; round < KNN; round++) {
        float mv[4]; int mj[4];
#pragma unroll
        for (int ii = 0; ii < 4; ii++) {
            mv[ii] = qv0[ii];
            mj[ii] = qe0[ii] * 64 + lane;
        }
#pragma unroll
        for (int off = 1; off < 64; off <<= 1)
#pragma unroll
            for (int ii = 0; ii < 4; ii++) {
                float ov = __shfl_xor(mv[ii], off);
                int   oj = __shfl_xor(mj[ii], off);
                bool less = (ov < mv[ii]) || (ov == mv[ii] && oj < mj[ii]);
                if (less) { mv[ii] = ov; mj[ii] = oj; }
            }
#pragma unroll
        for (int ii = 0; ii < 4; ii++) {
            if (lane == round) myj[ii] = mj[ii];
            if ((mj[ii] & 63) == lane) {         // unique owner (j unique)
                qv0[ii] = qv1[ii]; qe0[ii] = qe1[ii];
                qv1[ii] = PADF;    qe1[ii] = 0;
                if (qv0[ii] >= PADF) {           // placeholder at head: refill
                    float v0 = PADF, v1 = PADF;
                    int e0 = 0, e1 = 0;
#pragma unroll
                    for (int e = 0; e < 16; e++) {
                        float s = (((used[ii] >> e) & 1u) == 0u) ? d2k[ii][e] : PADF;
                        bool b0 = (s < v0);
                        bool b1 = (s < v1) && !b0;
                        v1 = b0 ? v0 : (b1 ? s : v1);
                        e1 = b0 ? e0 : (b1 ? e : e1);
                        v0 = b0 ? s : v0;
                        e0 = b0 ? e : e0;
                    }
                    qv0[ii] = v0; qe0[ii] = e0;
                    qv1[ii] = v1; qe1[ii] = e1;
                    used[ii] |= ((v0 < PADF) ? (1u << e0) : 0u)
                              | ((v1 < PADF) ? (1u << e1) : 0u);
                }
            }
        }
    }

    // ---- write knn: lane r holds winner of round r ------------------------
#pragma unroll
    for (int ii = 0; ii < 4; ii++) {
        int i_loc = i0 + w * 4 + ii;
        if (lane < KNN && i_loc < NPG)
            knn[(size_t)(g * NPG + i_loc) * KNN + lane] = g * NPG + myj[ii];
    }

    // ---- fused TU for this block's 16 rows (d2k/myj dead -> low pressure) -
    __syncthreads();                     // weight ds_writes visible to all
    {
        int nl = lane >> 4, cg = lane & 15;
        int node = w * 4 + nl;           // 0..15
        int i_loc = i0 + node;
        float4 tT = make_float4(0.f, 0.f, 0.f, 0.f);
        float4 tU = make_float4(0.f, 0.f, 0.f, 0.f);
#pragma unroll 4
        for (int e = 0; e < H; e++) {
            float hv = shi[node * H + e];
            float4 wd = *(const float4*)(&shj[0][e * H + cg * 4]);
            float4 w2 = *(const float4*)(&shj[1][e * H + cg * 4]);
            tT.x += hv * wd.x; tT.y += hv * wd.y; tT.z += hv * wd.z; tT.w += hv * wd.w;
            tU.x += hv * w2.x; tU.y += hv * w2.y; tU.z += hv * w2.z; tU.w += hv * w2.w;
        }
        float4 bb = *(const float4*)(bl + cg * 4);
        tT.x += bb.x; tT.y += bb.y; tT.z += bb.z; tT.w += bb.w;
        if (i_loc < NPG) {
            int gi = g * NPG + i_loc;
            *(float4*)(T + (size_t)gi * H + cg * 4) = tT;
            *(float4*)(U + (size_t)gi * H + cg * 4) = tU;
        }
    }
}

// ---------------------------------------------------------------------------
// Aggregate: h_new[i][c] = h[i][c] + a*ELU(sel_k (T[i][c]+U[j_k][c])) + (be - a*m)
// sel = max if a>=0 else min (ELU monotone). Also writes sq(h_new).
__global__ __launch_bounds__(256) void k_aggr(
    const float* __restrict__ hsrc, const float* __restrict__ T, const float* __restrict__ U,
    const int* __restrict__ knn,
    const float* __restrict__ bn_g, const float* __restrict__ bn_b,
    const float* __restrict__ bn_m, const float* __restrict__ bn_v,
    float* __restrict__ hdst, float* __restrict__ sqdst)
{
    int t = threadIdx.x, w = t >> 6, lane = t & 63;
    int i = blockIdx.x * 4 + w;
    float a = bn_g[lane] * rsqrtf(bn_v[lane] + EPS_BN);
    float cshift = bn_b[lane] - a * bn_m[lane];
    float tv = T[(size_t)i * H + lane];
    int idx[KNN];
#pragma unroll
    for (int k = 0; k < KNN; k++) idx[k] = knn[(size_t)i * KNN + k];
    float mx = -INFF, mn = INFF;
#pragma unroll
    for (int k = 0; k < KNN; k++) {
        float z = tv + U[(size_t)idx[k] * H + lane];
        mx = fmaxf(mx, z); mn = fminf(mn, z);
    }
    float zsel = (a >= 0.f) ? mx : mn;
    float e = zsel > 0.f ? zsel : expm1f(zsel);
    float val = hsrc[(size_t)i * H + lane] + a * e + cshift;
    hdst[(size_t)i * H + lane] = val;
    float s = val * val;
#pragma unroll
    for (int off = 32; off > 0; off >>= 1) s += __shfl_xor(s, off);
    if (lane == 0) sqdst[i] = s;
}

// ---------------------------------------------------------------------------
// Output heads. 16 nodes/block (wave per node, 4 reps). out layout:
// [0,128000): out [16000,8] | [128000,144000): sp | [144000,160000): batch (f32)
__global__ __launch_bounds__(256) void k_heads(
    const float* __restrict__ h,
    const float* __restrict__ oW1, const float* __restrict__ ob1,
    const float* __restrict__ oW2, const float* __restrict__ ob2,
    const float* __restrict__ oW3, const float* __restrict__ ob3,
    const float* __restrict__ pW1, const float* __restrict__ pb1,
    const float* __restrict__ pW2, const float* __restrict__ pb2,
    const float* __restrict__ pW3, const float* __restrict__ pb3,
    float* __restrict__ out)
{
    __shared__ float soW1[H * 64], soW2[64 * 32], soW3[32 * CD];
    __shared__ float spW1s[H * 64], spW2s[64 * 32], spW3s[32];
    __shared__ float sob1[64], sob2[32], sob3[CD], spb1s[64], spb2s[32], spb3s[1];
    __shared__ float sh[4][H];
    __shared__ float sa[4][64], ssp[4][64];
    __shared__ float so2[4][32], ssp2[4][32];

    int t = threadIdx.x, w = t >> 6, lane = t & 63;
    for (int ix = t; ix < H * 64; ix += 256) { soW1[ix] = oW1[ix]; spW1s[ix] = pW1[ix]; }
    for (int ix = t; ix < 64 * 32; ix += 256) { soW2[ix] = oW2[ix]; spW2s[ix] = pW2[ix]; }
    for (int ix = t; ix < 32 * CD; ix += 256) soW3[ix] = oW3[ix];
    if (t < 32) spW3s[t] = pW3[t];
    if (t < 64) { sob1[t] = ob1[t]; spb1s[t] = pb1[t]; }
    if (t < 32) { sob2[t] = ob2[t]; spb2s[t] = pb2[t]; }
    if (t < CD) sob3[t] = ob3[t];
    if (t == 0) spb3s[0] = pb3[0];
    __syncthreads();

    for (int rep = 0; rep < 4; rep++) {
        int i = blockIdx.x * 16 + rep * 4 + w;
        sh[w][lane] = h[(size_t)i * H + lane];
        __syncthreads();
        float a1 = sob1[lane], p1 = spb1s[lane];
#pragma unroll
        for (int k = 0; k < H; k++) {
            float hv = sh[w][k];
            a1 += hv * soW1[k * 64 + lane];
            p1 += hv * spW1s[k * 64 + lane];
        }
        a1 = a1 > 0.f ? a1 : expm1f(a1);
        p1 = p1 > 0.f ? p1 : expm1f(p1);
        sa[w][lane] = a1; ssp[w][lane] = p1;
        __syncthreads();
        if (lane < 32) {
            float o2 = sob2[lane], q2 = spb2s[lane];
#pragma unroll
            for (int k = 0; k < 64; k++) {
                o2 += sa[w][k] * soW2[k * 32 + lane];
                q2 += ssp[w][k] * spW2s[k * 32 + lane];
            }
            o2 = o2 > 0.f ? o2 : expm1f(o2);
            q2 = q2 > 0.f ? q2 : expm1f(q2);
            so2[w][lane] = o2; ssp2[w][lane] = q2;
        }
        __syncthreads();
        if (lane < CD) {
            float o3 = sob3[lane];
#pragma unroll
            for (int k = 0; k < 32; k++) o3 += so2[w][k] * soW3[k * CD + lane];
            out[(size_t)i * CD + lane] = o3;
        }
        if (lane == 32) {
            float s3 = spb3s[0];
#pragma unroll
            for (int k = 0; k < 32; k++) s3 += ssp2[w][k] * spW3s[k];
            out[(size_t)N_NODES * CD + i] = s3;
        }
        if (lane == 33) out[(size_t)N_NODES * CD + N_NODES + i] = (float)(i / NPG);
        __syncthreads();
    }
}

// ---------------------------------------------------------------------------
extern "C" void kernel_launch(void* const* d_in, const int* in_sizes, int n_in,
                              void* d_out, int out_size, void* d_ws, size_t ws_size,
                              hipStream_t stream)
{
    const float* x     = (const float*)d_in[0];
    // d_in[1] = batch (values reproduced analytically)
    const float* lcW1  = (const float*)d_in[2];  const float* lcb1 = (const float*)d_in[3];
    const float* lcW2  = (const float*)d_in[4];  const float* lcb2 = (const float*)d_in[5];
    const float* convW = (const float*)d_in[6];  const float* convb = (const float*)d_in[7];
    const float* bn_g  = (const float*)d_in[8];  const float* bn_b = (const float*)d_in[9];
    const float* bn_m  = (const float*)d_in[10]; const float* bn_v = (const float*)d_in[11];
    const float* outW1 = (const float*)d_in[12]; const float* outb1 = (const float*)d_in[13];
    const float* outW2 = (const float*)d_in[14]; const float* outb2 = (const float*)d_in[15];
    const float* outW3 = (const float*)d_in[16]; const float* outb3 = (const float*)d_in[17];
    const float* spW1  = (const float*)d_in[18]; const float* spb1 = (const float*)d_in[19];
    const float* spW2  = (const float*)d_in[20]; const float* spb2 = (const float*)d_in[21];
    const float* spW3  = (const float*)d_in[22]; const float* spb3 = (const float*)d_in[23];

    float* ws  = (float*)d_ws;
    float* hA  = ws;                       // 1,024,000 floats
    float* hB  = hA + (size_t)N_NODES * H;
    float* sqA = hB + (size_t)N_NODES * H;
    float* sqB = sqA + N_NODES;
    float* T   = sqB + N_NODES;
    float* U   = T + (size_t)N_NODES * H;
    int*   knn = (int*)(U + (size_t)N_NODES * H);

    k_lc_encode<<<N_NODES / 4, 256, 0, stream>>>(x, lcW1, lcb1, lcW2, lcb2, hA, sqA);

    float* src = hA; float* ssq = sqA; float* dst = hB; float* dsq = sqB;
    for (int l = 0; l < NLAYERS; l++) {
        k_knn<<<NGRAPH * IBLK, 256, 0, stream>>>(src, ssq, knn,
                                                 convW + (size_t)l * 2 * H * H,
                                                 convb + (size_t)l * H, T, U);
        k_aggr<<<N_NODES / 4, 256, 0, stream>>>(src, T, U, knn,
                                                bn_g + (size_t)l * H, bn_b + (size_t)l * H,
                                                bn_m + (size_t)l * H, bn_v + (size_t)l * H,
                                                dst, dsq);
        float* tmp = src; src = dst; dst = tmp;
        tmp = ssq; ssq = dsq; dsq = tmp;
    }

    k_heads<<<N_NODES / 16, 256, 0, stream>>>(src,
        outW1, outb1, outW2, outb2, outW3, outb3,
        spW1, spb1, spW2, spb2, spW3, spb3, (float*)d_out);
}